// Round 2
// baseline (229.854 us; speedup 1.0000x reference)
//
#include <hip/hip_runtime.h>

// Problem constants (fixed by setup_inputs)
#define NB 16
#define NQ 500
#define NC 256
#define NHW 64
#define MR 8000            // B*Q rows
#define KD 9216            // GEMM1 K = 36*256

typedef float f32x4 __attribute__((ext_vector_type(4)));
typedef __bf16 bf16x8 __attribute__((ext_vector_type(8)));
typedef unsigned short ushortx8 __attribute__((ext_vector_type(8)));

__device__ __forceinline__ unsigned short f2bf(float f) {
  unsigned int u = __builtin_bit_cast(unsigned int, f);
  u += 0x7fffu + ((u >> 16) & 1u);   // round-to-nearest-even
  return (unsigned short)(u >> 16);
}

// ---------------------------------------------------------------------------
// Kernel 1: points [B,Q,4,2]  (output 2, also kept in ws for the gather)
// points[...,0] = 2*poly(coeffs polys[b,q,4..8)) - 1 ; [...,1] from coeffs 0..4
// a = linspace(0,1,4) in fp32
__global__ void k_points(const float* __restrict__ polys,
                         float* __restrict__ outp, float* __restrict__ wsp) {
  int n = blockIdx.x * 256 + threadIdx.x;
  if (n >= MR) return;
  f32x4 ca = *(const f32x4*)(polys + (size_t)n * 8);
  f32x4 cb = *(const f32x4*)(polys + (size_t)n * 8 + 4);
  const float av[4] = {0.0f, 0.33333334f, 0.66666669f, 1.0f};
#pragma unroll
  for (int s = 0; s < 4; ++s) {
    float a1 = av[s], a2 = a1 * a1, a3 = a2 * a1;
    float v0 = ca.x * a3 + ca.y * a2 + ca.z * a1 + ca.w;  // comp c=0 -> points[...,1]
    float v1 = cb.x * a3 + cb.y * a2 + cb.z * a1 + cb.w;  // comp c=1 -> points[...,0]
    float pt0 = 2.0f * v1 - 1.0f;
    float pt1 = 2.0f * v0 - 1.0f;
    outp[(size_t)n * 8 + s * 2 + 0] = pt0;
    outp[(size_t)n * 8 + s * 2 + 1] = pt1;
    wsp[(size_t)n * 8 + s * 2 + 0] = pt0;
    wsp[(size_t)n * 8 + s * 2 + 1] = pt1;
  }
}

// ---------------------------------------------------------------------------
// Kernel 2: permute Wk [o, np*256+c, k, l] -> fragment-linear bf16 W2s[t>>3][o][t&7]
// with GEMM K index t = (np*9 + k*3 + l)*256 + c
__global__ void k_permwk(const float* __restrict__ Wk,
                         unsigned short* __restrict__ W2s) {
  int tid = blockIdx.x * 256 + threadIdx.x;
  if (tid >= (KD / 8) * NC) return;      // 294912
  int o = tid & 255;
  int th = tid >> 8;                     // 0..1151  (= t>>3)
  int r = th >> 5;                       // sample slot 0..35
  int cbase = (th & 31) * 8;
  int np = r / 9;
  int kl = r - np * 9;
  int kk = kl / 3;
  int ll = kl - kk * 3;
  const float* src = Wk + (size_t)o * KD + (size_t)(np * 256 + cbase) * 9 + kk * 3 + ll;
  ushortx8 v;
#pragma unroll
  for (int j = 0; j < 8; ++j) v[j] = f2bf(src[(size_t)j * 9]);
  *(ushortx8*)(W2s + (size_t)th * 2048 + o * 8) = v;
}

// Kernel 2b: permute Wp [o][j] -> fragment-linear bf16 WPs[j>>3][o][j&7]
__global__ void k_permwp(const float* __restrict__ Wp,
                         unsigned short* __restrict__ WPs) {
  int tid = blockIdx.x * 256 + threadIdx.x;
  if (tid >= 32 * 256) return;
  int o = tid & 255;
  int th = tid >> 8;                     // 0..31
  const float* src = Wp + (size_t)o * 256 + th * 8;
  ushortx8 v;
#pragma unroll
  for (int j = 0; j < 8; ++j) v[j] = f2bf(src[j]);
  *(ushortx8*)(WPs + (size_t)th * 2048 + o * 8) = v;
}

// ---------------------------------------------------------------------------
// Kernel 3: fused gather + GEMM1 (+bk, relu) -> CR1 bf16 [8000][256]
// Block: 32 rows x 256 cols, 512 threads (8 waves, each o-range 32).
// K-loop over 36 sample slots; per slot gather 32x256 bf16 A-tile into LDS.
__global__ __launch_bounds__(512) void k_gemm1(
    const float* __restrict__ mem, const float* __restrict__ pts,
    const unsigned short* __restrict__ W2s, const float* __restrict__ bk,
    unsigned short* __restrict__ CR1) {
  __shared__ __align__(16) unsigned short Alds[1024 * 8];  // 16 KB

  const int tid = threadIdx.x;
  const int n0 = blockIdx.x * 32;
  const int lane = tid & 63;
  const int wave = tid >> 6;   // 0..7
  const int lr = lane & 15;
  const int ksub = lane >> 4;
  const int o0 = wave * 32;

  // gather task assignment: low 5 bits = c-chunk (coalesced), high bits = row
  const int gchunk = tid & 31;
  const int gm0 = tid >> 5;    // 0..15 ; tasks handle rows gm0, gm0+16

  const int n_a = n0 + gm0;
  const int n_b = n0 + gm0 + 16;
  const int b_a = n_a / NQ;
  const int b_b = n_b / NQ;
  const float* const mem_a = mem + (size_t)b_a * (NHW * NHW * NC);
  const float* const mem_b = mem + (size_t)b_b * (NHW * NHW * NC);

  // delta tables indexed by mesh slot mm = r>>2 (all values exact in fp32)
  const float DHX[9] = {-0.0625f, -0.0625f, -0.0625f, -0.015625f, -0.015625f,
                        -0.015625f, 0.03125f, 0.03125f, 0.03125f};
  const float DWY[9] = {-0.0625f, -0.015625f, 0.03125f, -0.0625f, -0.015625f,
                        0.03125f, -0.0625f, -0.015625f, 0.03125f};

  f32x4 acc[2][2] = {};

  for (int r = 0; r < 36; ++r) {
    const int s = r & 3;
    const int mm = r >> 2;
    __syncthreads();
#pragma unroll
    for (int task = 0; task < 2; ++task) {
      const int m = gm0 + task * 16;
      const int n = (task == 0) ? n_a : n_b;
      const float* mb = (task == 0) ? mem_a : mem_b;
      const float p0 = pts[(size_t)n * 8 + s * 2 + 0];
      const float p1 = pts[(size_t)n * 8 + s * 2 + 1];
      // NOTE the reference's swap: grid[...,0] (from points[...,0]+delta_h)
      // drives the COLUMN coordinate, grid[...,1] drives the ROW.
      const float gx = (p0 + DHX[mm] + 1.0f) * 0.5f * 63.0f;  // column
      const float gy = (p1 + DWY[mm] + 1.0f) * 0.5f * 63.0f;  // row
      const float x0f = floorf(gx), y0f = floorf(gy);
      const float fx = gx - x0f, fy = gy - y0f;
      const int ix0 = (int)x0f, iy0 = (int)y0f;
      const int ix1 = ix0 + 1, iy1 = iy0 + 1;
      const float vx0 = (ix0 >= 0 && ix0 < NHW) ? 1.0f : 0.0f;
      const float vx1 = (ix1 >= 0 && ix1 < NHW) ? 1.0f : 0.0f;
      const float vy0 = (iy0 >= 0 && iy0 < NHW) ? 1.0f : 0.0f;
      const float vy1 = (iy1 >= 0 && iy1 < NHW) ? 1.0f : 0.0f;
      const float w00 = (1.0f - fy) * (1.0f - fx) * vy0 * vx0;
      const float w01 = (1.0f - fy) * fx * vy0 * vx1;
      const float w10 = fy * (1.0f - fx) * vy1 * vx0;
      const float w11 = fy * fx * vy1 * vx1;
      const int cx0 = min(max(ix0, 0), NHW - 1), cx1 = min(max(ix1, 0), NHW - 1);
      const int cy0 = min(max(iy0, 0), NHW - 1), cy1 = min(max(iy1, 0), NHW - 1);
      const float* q00 = mb + (size_t)(cy0 * NHW + cx0) * NC + gchunk * 8;
      const float* q01 = mb + (size_t)(cy0 * NHW + cx1) * NC + gchunk * 8;
      const float* q10 = mb + (size_t)(cy1 * NHW + cx0) * NC + gchunk * 8;
      const float* q11 = mb + (size_t)(cy1 * NHW + cx1) * NC + gchunk * 8;
      f32x4 v00a = *(const f32x4*)q00, v00b = *(const f32x4*)(q00 + 4);
      f32x4 v01a = *(const f32x4*)q01, v01b = *(const f32x4*)(q01 + 4);
      f32x4 v10a = *(const f32x4*)q10, v10b = *(const f32x4*)(q10 + 4);
      f32x4 v11a = *(const f32x4*)q11, v11b = *(const f32x4*)(q11 + 4);
      f32x4 ra = v00a * w00 + v01a * w01 + v10a * w10 + v11a * w11;
      f32x4 rb = v00b * w00 + v01b * w01 + v10b * w10 + v11b * w11;
      ushortx8 pk;
      pk[0] = f2bf(ra.x); pk[1] = f2bf(ra.y); pk[2] = f2bf(ra.z); pk[3] = f2bf(ra.w);
      pk[4] = f2bf(rb.x); pk[5] = f2bf(rb.y); pk[6] = f2bf(rb.z); pk[7] = f2bf(rb.w);
      // XOR slot swizzle: bank-uniform for both the write (lanes vary chunk)
      // and the fragment read (lanes vary m)
      const int slot = gchunk * 32 + (m ^ (gchunk & 15));
      *(ushortx8*)(Alds + slot * 8) = pk;
    }
    __syncthreads();
    const size_t rbase = (size_t)r * 32;
#pragma unroll
    for (int kstep = 0; kstep < 8; ++kstep) {
      const int chunk = kstep * 4 + ksub;
      const int sa0 = chunk * 32 + (lr ^ (chunk & 15));
      const int sa1 = chunk * 32 + ((16 + lr) ^ (chunk & 15));
      ushortx8 ua0 = *(const ushortx8*)(Alds + sa0 * 8);
      ushortx8 ua1 = *(const ushortx8*)(Alds + sa1 * 8);
      const unsigned short* bp = W2s + (rbase + chunk) * 2048 + (o0 + lr) * 8;
      ushortx8 ub0 = *(const ushortx8*)bp;
      ushortx8 ub1 = *(const ushortx8*)(bp + 128);
      bf16x8 fa0 = __builtin_bit_cast(bf16x8, ua0);
      bf16x8 fa1 = __builtin_bit_cast(bf16x8, ua1);
      bf16x8 fb0 = __builtin_bit_cast(bf16x8, ub0);
      bf16x8 fb1 = __builtin_bit_cast(bf16x8, ub1);
      acc[0][0] = __builtin_amdgcn_mfma_f32_16x16x32_bf16(fa0, fb0, acc[0][0], 0, 0, 0);
      acc[1][0] = __builtin_amdgcn_mfma_f32_16x16x32_bf16(fa1, fb0, acc[1][0], 0, 0, 0);
      acc[0][1] = __builtin_amdgcn_mfma_f32_16x16x32_bf16(fa0, fb1, acc[0][1], 0, 0, 0);
      acc[1][1] = __builtin_amdgcn_mfma_f32_16x16x32_bf16(fa1, fb1, acc[1][1], 0, 0, 0);
    }
  }
  // epilogue: + bk, relu, bf16 store. C/D: col=lane&15, row=(lane>>4)*4+reg
#pragma unroll
  for (int mf = 0; mf < 2; ++mf) {
#pragma unroll
    for (int nf = 0; nf < 2; ++nf) {
      const int o = o0 + nf * 16 + lr;
      const float bko = bk[o];
#pragma unroll
      for (int reg = 0; reg < 4; ++reg) {
        const int mrow = mf * 16 + ksub * 4 + reg;
        float v = acc[mf][nf][reg] + bko;
        v = v > 0.0f ? v : 0.0f;
        CR1[(size_t)(n0 + mrow) * 256 + o] = f2bf(v);
      }
    }
  }
}

// ---------------------------------------------------------------------------
// Kernel 4: GEMM2  out[n,o] = sum_j CR1[n,j]*Wp[o,j] + bp[o]
__global__ __launch_bounds__(256) void k_gemm2(
    const unsigned short* __restrict__ CR1, const unsigned short* __restrict__ WPs,
    const float* __restrict__ bp, float* __restrict__ outc) {
  const int tid = threadIdx.x;
  const int n0 = blockIdx.x * 32;
  const int lane = tid & 63;
  const int wave = tid >> 6;  // 0..3
  const int lr = lane & 15;
  const int ksub = lane >> 4;
  const int o0 = wave * 64;
  f32x4 acc[2][4] = {};
#pragma unroll
  for (int kstep = 0; kstep < 8; ++kstep) {
    const int t0 = kstep * 32 + ksub * 8;
    ushortx8 ua0 = *(const ushortx8*)(CR1 + (size_t)(n0 + lr) * 256 + t0);
    ushortx8 ua1 = *(const ushortx8*)(CR1 + (size_t)(n0 + 16 + lr) * 256 + t0);
    bf16x8 fa0 = __builtin_bit_cast(bf16x8, ua0);
    bf16x8 fa1 = __builtin_bit_cast(bf16x8, ua1);
    const int chunk = kstep * 4 + ksub;
#pragma unroll
    for (int nf = 0; nf < 4; ++nf) {
      ushortx8 ub = *(const ushortx8*)(WPs + (size_t)chunk * 2048 + (o0 + nf * 16 + lr) * 8);
      bf16x8 fb = __builtin_bit_cast(bf16x8, ub);
      acc[0][nf] = __builtin_amdgcn_mfma_f32_16x16x32_bf16(fa0, fb, acc[0][nf], 0, 0, 0);
      acc[1][nf] = __builtin_amdgcn_mfma_f32_16x16x32_bf16(fa1, fb, acc[1][nf], 0, 0, 0);
    }
  }
#pragma unroll
  for (int mf = 0; mf < 2; ++mf) {
#pragma unroll
    for (int nf = 0; nf < 4; ++nf) {
      const int o = o0 + nf * 16 + lr;
      const float bpo = bp[o];
#pragma unroll
      for (int reg = 0; reg < 4; ++reg) {
        const int mrow = mf * 16 + ksub * 4 + reg;
        outc[(size_t)(n0 + mrow) * 256 + o] = acc[mf][nf][reg] + bpo;
      }
    }
  }
}

// ---------------------------------------------------------------------------
extern "C" void kernel_launch(void* const* d_in, const int* in_sizes, int n_in,
                              void* d_out, int out_size, void* d_ws, size_t ws_size,
                              hipStream_t stream) {
  (void)in_sizes; (void)n_in; (void)out_size; (void)ws_size;
  const float* polys = (const float*)d_in[1];
  const float* mem   = (const float*)d_in[2];
  const float* Wk    = (const float*)d_in[4];
  const float* bk    = (const float*)d_in[5];
  const float* Wp    = (const float*)d_in[6];
  const float* bp    = (const float*)d_in[7];
  float* out = (float*)d_out;
  float* out_pts = out + (size_t)MR * NC;   // second output: points

  // ws layout (9.2 MB total)
  unsigned short* W2s = (unsigned short*)d_ws;                       // 4,718,592 B
  unsigned short* WPs = (unsigned short*)((char*)d_ws + 4718592);    //   131,072 B
  float*          PTS = (float*)((char*)d_ws + 4849664);             //   256,000 B
  unsigned short* CR1 = (unsigned short*)((char*)d_ws + 5105664);    // 4,096,000 B

  hipLaunchKernelGGL(k_points, dim3(32), dim3(256), 0, stream, polys, out_pts, PTS);
  hipLaunchKernelGGL(k_permwk, dim3(1152), dim3(256), 0, stream, Wk, W2s);
  hipLaunchKernelGGL(k_permwp, dim3(32), dim3(256), 0, stream, Wp, WPs);
  hipLaunchKernelGGL(k_gemm1, dim3(250), dim3(512), 0, stream, mem, PTS, W2s, bk, CR1);
  hipLaunchKernelGGL(k_gemm2, dim3(250), dim3(256), 0, stream, CR1, WPs, bp, out);
}

// Round 3
// 174.322 us; speedup vs baseline: 1.3186x; 1.3186x over previous
//
#include <hip/hip_runtime.h>

// Problem constants (fixed by setup_inputs)
#define NB 16
#define NQ 500
#define NC 256
#define NHW 64
#define MR 8000            // B*Q rows
#define KD 9216            // GEMM1 K = 36*256

typedef float f32x4 __attribute__((ext_vector_type(4)));
typedef __bf16 bf16x8 __attribute__((ext_vector_type(8)));
typedef unsigned short ushortx8 __attribute__((ext_vector_type(8)));
typedef unsigned short ushortx4 __attribute__((ext_vector_type(4)));

__device__ __forceinline__ unsigned short f2bf(float f) {
  unsigned int u = __builtin_bit_cast(unsigned int, f);
  u += 0x7fffu + ((u >> 16) & 1u);   // round-to-nearest-even
  return (unsigned short)(u >> 16);
}

// ---------------------------------------------------------------------------
// Kernel 1: points [B,Q,4,2]  (output 2, also kept in ws for the gather)
__global__ void k_points(const float* __restrict__ polys,
                         float* __restrict__ outp, float* __restrict__ wsp) {
  int n = blockIdx.x * 256 + threadIdx.x;
  if (n >= MR) return;
  f32x4 ca = *(const f32x4*)(polys + (size_t)n * 8);
  f32x4 cb = *(const f32x4*)(polys + (size_t)n * 8 + 4);
  const float av[4] = {0.0f, 0.33333334f, 0.66666669f, 1.0f};
#pragma unroll
  for (int s = 0; s < 4; ++s) {
    float a1 = av[s], a2 = a1 * a1, a3 = a2 * a1;
    float v0 = ca.x * a3 + ca.y * a2 + ca.z * a1 + ca.w;
    float v1 = cb.x * a3 + cb.y * a2 + cb.z * a1 + cb.w;
    float pt0 = 2.0f * v1 - 1.0f;
    float pt1 = 2.0f * v0 - 1.0f;
    outp[(size_t)n * 8 + s * 2 + 0] = pt0;
    outp[(size_t)n * 8 + s * 2 + 1] = pt1;
    wsp[(size_t)n * 8 + s * 2 + 0] = pt0;
    wsp[(size_t)n * 8 + s * 2 + 1] = pt1;
  }
}

// ---------------------------------------------------------------------------
// Kernel 2: permute Wk -> fragment-linear bf16 W2s[t>>3][o][t&7]
__global__ void k_permwk(const float* __restrict__ Wk,
                         unsigned short* __restrict__ W2s) {
  int tid = blockIdx.x * 256 + threadIdx.x;
  if (tid >= (KD / 8) * NC) return;      // 294912
  int o = tid & 255;
  int th = tid >> 8;                     // 0..1151  (= t>>3)
  int r = th >> 5;                       // sample slot 0..35
  int cbase = (th & 31) * 8;
  int np = r / 9;
  int kl = r - np * 9;
  int kk = kl / 3;
  int ll = kl - kk * 3;
  const float* src = Wk + (size_t)o * KD + (size_t)(np * 256 + cbase) * 9 + kk * 3 + ll;
  ushortx8 v;
#pragma unroll
  for (int j = 0; j < 8; ++j) v[j] = f2bf(src[(size_t)j * 9]);
  *(ushortx8*)(W2s + (size_t)th * 2048 + o * 8) = v;
}

// Kernel 2b: permute Wp -> fragment-linear bf16 WPs[j>>3][o][j&7]
__global__ void k_permwp(const float* __restrict__ Wp,
                         unsigned short* __restrict__ WPs) {
  int tid = blockIdx.x * 256 + threadIdx.x;
  if (tid >= 32 * 256) return;
  int o = tid & 255;
  int th = tid >> 8;
  const float* src = Wp + (size_t)o * 256 + th * 8;
  ushortx8 v;
#pragma unroll
  for (int j = 0; j < 8; ++j) v[j] = f2bf(src[j]);
  *(ushortx8*)(WPs + (size_t)th * 2048 + o * 8) = v;
}

// ---------------------------------------------------------------------------
// Kernel 3: fused gather + GEMM1, split-K over the 36 sample slots.
// Grid bid = x + 8*(kk + K*j): x=bid&7, kk=(bid>>3)%K, j=bid/(8K); tile t=x+8j.
// All K splits of a tile share bid%8 -> same XCD -> L2 reuse of gather window.
// PART != null: write fp32 partial [kk][8000][256]. PART == null (K=1): direct
// bias+relu+bf16 into CR1.
__global__ __launch_bounds__(512) void k_gemm1(
    const float* __restrict__ mem, const float* __restrict__ pts,
    const unsigned short* __restrict__ W2s, const float* __restrict__ bk,
    float* __restrict__ PART, unsigned short* __restrict__ CR1, int K) {
  __shared__ __align__(16) unsigned short Alds[1024 * 8];  // 16 KB

  const int bid = blockIdx.x;
  const int x = bid & 7;
  const int kk8 = (bid >> 3) % K;
  const int j = bid / (8 * K);
  const int t = x + 8 * j;
  if (t >= 250) return;
  const int nsl = 36 / K;
  const int r0 = kk8 * nsl;

  const int tid = threadIdx.x;
  const int n0 = t * 32;
  const int lane = tid & 63;
  const int wave = tid >> 6;   // 0..7
  const int lr = lane & 15;
  const int ksub = lane >> 4;
  const int o0 = wave * 32;

  const int gchunk = tid & 31;
  const int gm0 = tid >> 5;    // 0..15 ; tasks handle rows gm0, gm0+16

  const int n_a = n0 + gm0;
  const int n_b = n0 + gm0 + 16;
  const int b_a = n_a / NQ;
  const int b_b = n_b / NQ;
  const float* const mem_a = mem + (size_t)b_a * (NHW * NHW * NC);
  const float* const mem_b = mem + (size_t)b_b * (NHW * NHW * NC);

  f32x4 acc[2][2] = {};

  for (int r = r0; r < r0 + nsl; ++r) {
    const int s = r & 3;
    const int mm = r >> 2;
    // delta(a) = (1.5a-2)/32, exact in fp32; DHX = delta(mm/3), DWY = delta(mm%3)
    const int mdiv = (mm * 11) >> 5;          // mm/3 for mm in [0,9)
    const int mmod = mm - 3 * mdiv;
    const float dhx = (1.5f * (float)mdiv - 2.0f) * 0.03125f;
    const float dwy = (1.5f * (float)mmod - 2.0f) * 0.03125f;
    __syncthreads();
#pragma unroll
    for (int task = 0; task < 2; ++task) {
      const int m = gm0 + task * 16;
      const int n = (task == 0) ? n_a : n_b;
      const float* mb = (task == 0) ? mem_a : mem_b;
      const float p0 = pts[(size_t)n * 8 + s * 2 + 0];
      const float p1 = pts[(size_t)n * 8 + s * 2 + 1];
      // grid[...,0] (points[...,0]+delta_h) drives COLUMN; [...,1] drives ROW.
      const float gx = (p0 + dhx + 1.0f) * 0.5f * 63.0f;  // column
      const float gy = (p1 + dwy + 1.0f) * 0.5f * 63.0f;  // row
      const float x0f = floorf(gx), y0f = floorf(gy);
      const float fx = gx - x0f, fy = gy - y0f;
      const int ix0 = (int)x0f, iy0 = (int)y0f;
      const int ix1 = ix0 + 1, iy1 = iy0 + 1;
      const float vx0 = (ix0 >= 0 && ix0 < NHW) ? 1.0f : 0.0f;
      const float vx1 = (ix1 >= 0 && ix1 < NHW) ? 1.0f : 0.0f;
      const float vy0 = (iy0 >= 0 && iy0 < NHW) ? 1.0f : 0.0f;
      const float vy1 = (iy1 >= 0 && iy1 < NHW) ? 1.0f : 0.0f;
      const float w00 = (1.0f - fy) * (1.0f - fx) * vy0 * vx0;
      const float w01 = (1.0f - fy) * fx * vy0 * vx1;
      const float w10 = fy * (1.0f - fx) * vy1 * vx0;
      const float w11 = fy * fx * vy1 * vx1;
      const int cx0 = min(max(ix0, 0), NHW - 1), cx1 = min(max(ix1, 0), NHW - 1);
      const int cy0 = min(max(iy0, 0), NHW - 1), cy1 = min(max(iy1, 0), NHW - 1);
      const float* q00 = mb + (size_t)(cy0 * NHW + cx0) * NC + gchunk * 8;
      const float* q01 = mb + (size_t)(cy0 * NHW + cx1) * NC + gchunk * 8;
      const float* q10 = mb + (size_t)(cy1 * NHW + cx0) * NC + gchunk * 8;
      const float* q11 = mb + (size_t)(cy1 * NHW + cx1) * NC + gchunk * 8;
      f32x4 v00a = *(const f32x4*)q00, v00b = *(const f32x4*)(q00 + 4);
      f32x4 v01a = *(const f32x4*)q01, v01b = *(const f32x4*)(q01 + 4);
      f32x4 v10a = *(const f32x4*)q10, v10b = *(const f32x4*)(q10 + 4);
      f32x4 v11a = *(const f32x4*)q11, v11b = *(const f32x4*)(q11 + 4);
      f32x4 ra = v00a * w00 + v01a * w01 + v10a * w10 + v11a * w11;
      f32x4 rb = v00b * w00 + v01b * w01 + v10b * w10 + v11b * w11;
      ushortx8 pk;
      pk[0] = f2bf(ra.x); pk[1] = f2bf(ra.y); pk[2] = f2bf(ra.z); pk[3] = f2bf(ra.w);
      pk[4] = f2bf(rb.x); pk[5] = f2bf(rb.y); pk[6] = f2bf(rb.z); pk[7] = f2bf(rb.w);
      const int slot = gchunk * 32 + (m ^ (gchunk & 15));
      *(ushortx8*)(Alds + slot * 8) = pk;
    }
    __syncthreads();
    const size_t rbase = (size_t)r * 32;
#pragma unroll
    for (int kstep = 0; kstep < 8; ++kstep) {
      const int chunk = kstep * 4 + ksub;
      const int sa0 = chunk * 32 + (lr ^ (chunk & 15));
      const int sa1 = chunk * 32 + ((16 + lr) ^ (chunk & 15));
      ushortx8 ua0 = *(const ushortx8*)(Alds + sa0 * 8);
      ushortx8 ua1 = *(const ushortx8*)(Alds + sa1 * 8);
      const unsigned short* bp = W2s + (rbase + chunk) * 2048 + (o0 + lr) * 8;
      ushortx8 ub0 = *(const ushortx8*)bp;
      ushortx8 ub1 = *(const ushortx8*)(bp + 128);
      bf16x8 fa0 = __builtin_bit_cast(bf16x8, ua0);
      bf16x8 fa1 = __builtin_bit_cast(bf16x8, ua1);
      bf16x8 fb0 = __builtin_bit_cast(bf16x8, ub0);
      bf16x8 fb1 = __builtin_bit_cast(bf16x8, ub1);
      acc[0][0] = __builtin_amdgcn_mfma_f32_16x16x32_bf16(fa0, fb0, acc[0][0], 0, 0, 0);
      acc[1][0] = __builtin_amdgcn_mfma_f32_16x16x32_bf16(fa1, fb0, acc[1][0], 0, 0, 0);
      acc[0][1] = __builtin_amdgcn_mfma_f32_16x16x32_bf16(fa0, fb1, acc[0][1], 0, 0, 0);
      acc[1][1] = __builtin_amdgcn_mfma_f32_16x16x32_bf16(fa1, fb1, acc[1][1], 0, 0, 0);
    }
  }
  // epilogue. C/D: col=lane&15, row=(lane>>4)*4+reg
  if (PART) {
    float* dst = PART + (size_t)kk8 * (MR * NC);
#pragma unroll
    for (int mf = 0; mf < 2; ++mf)
#pragma unroll
      for (int nf = 0; nf < 2; ++nf) {
        const int o = o0 + nf * 16 + lr;
#pragma unroll
        for (int reg = 0; reg < 4; ++reg) {
          const int mrow = mf * 16 + ksub * 4 + reg;
          dst[(size_t)(n0 + mrow) * 256 + o] = acc[mf][nf][reg];
        }
      }
  } else {
#pragma unroll
    for (int mf = 0; mf < 2; ++mf)
#pragma unroll
      for (int nf = 0; nf < 2; ++nf) {
        const int o = o0 + nf * 16 + lr;
        const float bko = bk[o];
#pragma unroll
        for (int reg = 0; reg < 4; ++reg) {
          const int mrow = mf * 16 + ksub * 4 + reg;
          float v = acc[mf][nf][reg] + bko;
          v = v > 0.0f ? v : 0.0f;
          CR1[(size_t)(n0 + mrow) * 256 + o] = f2bf(v);
        }
      }
  }
}

// ---------------------------------------------------------------------------
// Kernel 3b: reduce K partials + bias + relu -> bf16 CR1
__global__ __launch_bounds__(256) void k_red(
    const float* __restrict__ PART, const float* __restrict__ bk,
    unsigned short* __restrict__ CR1, int K) {
  int gid = blockIdx.x * 256 + threadIdx.x;     // one f32x4 (4 outputs) each
  size_t idx4 = (size_t)gid * 4;
  if (idx4 >= (size_t)MR * NC) return;
  f32x4 sum = *(const f32x4*)(PART + idx4);
  for (int k = 1; k < K; ++k)
    sum += *(const f32x4*)(PART + (size_t)k * (MR * NC) + idx4);
  f32x4 bv = *(const f32x4*)(bk + (idx4 & 255));
  sum += bv;
  ushortx4 pk;
#pragma unroll
  for (int e = 0; e < 4; ++e) {
    float v = sum[e] > 0.0f ? sum[e] : 0.0f;
    pk[e] = f2bf(v);
  }
  *(ushortx4*)(CR1 + idx4) = pk;
}

// ---------------------------------------------------------------------------
// Kernel 4: GEMM2  out[n,o] = sum_j CR1[n,j]*Wp[o,j] + bp[o]  (16-row tiles)
__global__ __launch_bounds__(256) void k_gemm2(
    const unsigned short* __restrict__ CR1, const unsigned short* __restrict__ WPs,
    const float* __restrict__ bp, float* __restrict__ outc) {
  const int tid = threadIdx.x;
  const int n0 = blockIdx.x * 16;
  const int lane = tid & 63;
  const int wave = tid >> 6;  // 0..3
  const int lr = lane & 15;
  const int ksub = lane >> 4;
  const int o0 = wave * 64;
  f32x4 acc[4] = {};
#pragma unroll
  for (int kstep = 0; kstep < 8; ++kstep) {
    const int t0 = kstep * 32 + ksub * 8;
    ushortx8 ua0 = *(const ushortx8*)(CR1 + (size_t)(n0 + lr) * 256 + t0);
    bf16x8 fa0 = __builtin_bit_cast(bf16x8, ua0);
    const int chunk = kstep * 4 + ksub;
#pragma unroll
    for (int nf = 0; nf < 4; ++nf) {
      ushortx8 ub = *(const ushortx8*)(WPs + (size_t)chunk * 2048 + (o0 + nf * 16 + lr) * 8);
      bf16x8 fb = __builtin_bit_cast(bf16x8, ub);
      acc[nf] = __builtin_amdgcn_mfma_f32_16x16x32_bf16(fa0, fb, acc[nf], 0, 0, 0);
    }
  }
#pragma unroll
  for (int nf = 0; nf < 4; ++nf) {
    const int o = o0 + nf * 16 + lr;
    const float bpo = bp[o];
#pragma unroll
    for (int reg = 0; reg < 4; ++reg) {
      const int mrow = ksub * 4 + reg;
      outc[(size_t)(n0 + mrow) * 256 + o] = acc[nf][reg] + bpo;
    }
  }
}

// ---------------------------------------------------------------------------
extern "C" void kernel_launch(void* const* d_in, const int* in_sizes, int n_in,
                              void* d_out, int out_size, void* d_ws, size_t ws_size,
                              hipStream_t stream) {
  (void)in_sizes; (void)n_in; (void)out_size;
  const float* polys = (const float*)d_in[1];
  const float* mem   = (const float*)d_in[2];
  const float* Wk    = (const float*)d_in[4];
  const float* bk    = (const float*)d_in[5];
  const float* Wp    = (const float*)d_in[6];
  const float* bp    = (const float*)d_in[7];
  float* out = (float*)d_out;
  float* out_pts = out + (size_t)MR * NC;   // second output: points

  // ws layout
  unsigned short* W2s = (unsigned short*)d_ws;                       // 4,718,592 B
  unsigned short* WPs = (unsigned short*)((char*)d_ws + 4718592);    //   131,072 B
  float*          PTS = (float*)((char*)d_ws + 4849664);             //   256,000 B
  unsigned short* CR1 = (unsigned short*)((char*)d_ws + 5105664);    // 4,096,000 B
  const size_t PART_OFF = 9201664;
  float*          PARTp = (float*)((char*)d_ws + PART_OFF);          // K*8,192,000 B

  int K = 1;
  if (ws_size >= PART_OFF + 4ull * 8192000ull) K = 4;
  else if (ws_size >= PART_OFF + 2ull * 8192000ull) K = 2;
  float* PART = (K > 1) ? PARTp : nullptr;

  hipLaunchKernelGGL(k_points, dim3(32), dim3(256), 0, stream, polys, out_pts, PTS);
  hipLaunchKernelGGL(k_permwk, dim3(1152), dim3(256), 0, stream, Wk, W2s);
  hipLaunchKernelGGL(k_permwp, dim3(32), dim3(256), 0, stream, Wp, WPs);
  hipLaunchKernelGGL(k_gemm1, dim3(256 * K), dim3(512), 0, stream,
                     mem, PTS, W2s, bk, PART, CR1, K);
  if (PART)
    hipLaunchKernelGGL(k_red, dim3(2000), dim3(256), 0, stream, PART, bk, CR1, K);
  hipLaunchKernelGGL(k_gemm2, dim3(500), dim3(256), 0, stream, CR1, WPs, bp, out);
}

// Round 5
// 134.758 us; speedup vs baseline: 1.7057x; 1.2936x over previous
//
#include <hip/hip_runtime.h>

// Problem constants (fixed by setup_inputs)
#define NB 16
#define NQ 500
#define NC 256
#define NHW 64
#define MR 8000            // B*Q rows
#define KD 9216            // GEMM1 K = 36*256

typedef float f32x4 __attribute__((ext_vector_type(4)));
typedef __bf16 bf16x8 __attribute__((ext_vector_type(8)));
typedef unsigned short ushortx8 __attribute__((ext_vector_type(8)));
typedef unsigned short ushortx4 __attribute__((ext_vector_type(4)));

__device__ __forceinline__ unsigned short f2bf(float f) {
  unsigned int u = __builtin_bit_cast(unsigned int, f);
  u += 0x7fffu + ((u >> 16) & 1u);   // round-to-nearest-even
  return (unsigned short)(u >> 16);
}

// ---------------------------------------------------------------------------
// Kernel 1: points [B,Q,4,2]  (output 2, also kept in ws for the gather)
__global__ void k_points(const float* __restrict__ polys,
                         float* __restrict__ outp, float* __restrict__ wsp) {
  int n = blockIdx.x * 256 + threadIdx.x;
  if (n >= MR) return;
  f32x4 ca = *(const f32x4*)(polys + (size_t)n * 8);
  f32x4 cb = *(const f32x4*)(polys + (size_t)n * 8 + 4);
  const float av[4] = {0.0f, 0.33333334f, 0.66666669f, 1.0f};
#pragma unroll
  for (int s = 0; s < 4; ++s) {
    float a1 = av[s], a2 = a1 * a1, a3 = a2 * a1;
    float v0 = ca.x * a3 + ca.y * a2 + ca.z * a1 + ca.w;
    float v1 = cb.x * a3 + cb.y * a2 + cb.z * a1 + cb.w;
    float pt0 = 2.0f * v1 - 1.0f;
    float pt1 = 2.0f * v0 - 1.0f;
    outp[(size_t)n * 8 + s * 2 + 0] = pt0;
    outp[(size_t)n * 8 + s * 2 + 1] = pt1;
    wsp[(size_t)n * 8 + s * 2 + 0] = pt0;
    wsp[(size_t)n * 8 + s * 2 + 1] = pt1;
  }
}

// ---------------------------------------------------------------------------
// Kernel 2: permute Wk -> fragment-linear bf16 W2s[t>>3][o][t&7]
__global__ void k_permwk(const float* __restrict__ Wk,
                         unsigned short* __restrict__ W2s) {
  int tid = blockIdx.x * 256 + threadIdx.x;
  if (tid >= (KD / 8) * NC) return;      // 294912
  int o = tid & 255;
  int th = tid >> 8;                     // 0..1151  (= t>>3)
  int r = th >> 5;                       // sample slot 0..35
  int cbase = (th & 31) * 8;
  int np = r / 9;
  int kl = r - np * 9;
  int kk = kl / 3;
  int ll = kl - kk * 3;
  const float* src = Wk + (size_t)o * KD + (size_t)(np * 256 + cbase) * 9 + kk * 3 + ll;
  ushortx8 v;
#pragma unroll
  for (int j = 0; j < 8; ++j) v[j] = f2bf(src[(size_t)j * 9]);
  *(ushortx8*)(W2s + (size_t)th * 2048 + o * 8) = v;
}

// Kernel 2b: permute Wp -> fragment-linear bf16 WPs[j>>3][o][j&7]
__global__ void k_permwp(const float* __restrict__ Wp,
                         unsigned short* __restrict__ WPs) {
  int tid = blockIdx.x * 256 + threadIdx.x;
  if (tid >= 32 * 256) return;
  int o = tid & 255;
  int th = tid >> 8;
  const float* src = Wp + (size_t)o * 256 + th * 8;
  ushortx8 v;
#pragma unroll
  for (int j = 0; j < 8; ++j) v[j] = f2bf(src[j]);
  *(ushortx8*)(WPs + (size_t)th * 2048 + o * 8) = v;
}

// ---------------------------------------------------------------------------
// Kernel 3: fused gather + GEMM1, split-K over the 36 sample slots.
// Block decomposition IDENTICAL to the verified round-3 kernel:
//   x=bid&7, kk8=(bid>>3)%K, j=bid/(8K), t=x+8j, guard t>=250
// (guard yields exactly j < tiles_x, tiles_x = 32,32,31,31,31,31,31,31).
// NEW (2 lines): contiguous reindex tt so XCD x owns tiles
// [32x - max(x-2,0), +tiles_x) -> per-XCD gather window ~2-3 batches.
__global__ __launch_bounds__(512) void k_gemm1(
    const float* __restrict__ mem, const float* __restrict__ pts,
    const unsigned short* __restrict__ W2s, const float* __restrict__ bk,
    float* __restrict__ PART, unsigned short* __restrict__ CR1, int K) {
  __shared__ __align__(16) unsigned short Alds[1024 * 8];  // 16 KB

  const int bid = blockIdx.x;
  const int x = bid & 7;
  const int kk8 = (bid >> 3) % K;
  const int j = bid / (8 * K);
  const int t = x + 8 * j;
  if (t >= 250) return;
  const int tt = 32 * x - ((x > 2) ? (x - 2) : 0) + j;   // contiguous tile id
  const int nsl = 36 / K;
  const int r0 = kk8 * nsl;

  const int tid = threadIdx.x;
  const int n0 = tt * 32;
  const int lane = tid & 63;
  const int wave = tid >> 6;   // 0..7
  const int lr = lane & 15;
  const int ksub = lane >> 4;
  const int o0 = wave * 32;

  const int gchunk = tid & 31;
  const int gm0 = tid >> 5;    // 0..15 ; tasks handle rows gm0, gm0+16

  const int n_a = n0 + gm0;
  const int n_b = n0 + gm0 + 16;
  const int b_a = n_a / NQ;
  const int b_b = n_b / NQ;
  const float* const mem_a = mem + (size_t)b_a * (NHW * NHW * NC);
  const float* const mem_b = mem + (size_t)b_b * (NHW * NHW * NC);

  f32x4 acc[2][2] = {};

  for (int r = r0; r < r0 + nsl; ++r) {
    const int s = r & 3;
    const int mm = r >> 2;
    // delta(a) = (1.5a-2)/32, exact in fp32; DHX = delta(mm/3), DWY = delta(mm%3)
    const int mdiv = (mm * 11) >> 5;          // mm/3 for mm in [0,9)
    const int mmod = mm - 3 * mdiv;
    const float dhx = (1.5f * (float)mdiv - 2.0f) * 0.03125f;
    const float dwy = (1.5f * (float)mmod - 2.0f) * 0.03125f;
    __syncthreads();
#pragma unroll
    for (int task = 0; task < 2; ++task) {
      const int m = gm0 + task * 16;
      const int n = (task == 0) ? n_a : n_b;
      const float* mb = (task == 0) ? mem_a : mem_b;
      const float p0 = pts[(size_t)n * 8 + s * 2 + 0];
      const float p1 = pts[(size_t)n * 8 + s * 2 + 1];
      // grid[...,0] (points[...,0]+delta_h) drives COLUMN; [...,1] drives ROW.
      const float gx = (p0 + dhx + 1.0f) * 0.5f * 63.0f;  // column
      const float gy = (p1 + dwy + 1.0f) * 0.5f * 63.0f;  // row
      const float x0f = floorf(gx), y0f = floorf(gy);
      const float fx = gx - x0f, fy = gy - y0f;
      const int ix0 = (int)x0f, iy0 = (int)y0f;
      const int ix1 = ix0 + 1, iy1 = iy0 + 1;
      const float vx0 = (ix0 >= 0 && ix0 < NHW) ? 1.0f : 0.0f;
      const float vx1 = (ix1 >= 0 && ix1 < NHW) ? 1.0f : 0.0f;
      const float vy0 = (iy0 >= 0 && iy0 < NHW) ? 1.0f : 0.0f;
      const float vy1 = (iy1 >= 0 && iy1 < NHW) ? 1.0f : 0.0f;
      const float w00 = (1.0f - fy) * (1.0f - fx) * vy0 * vx0;
      const float w01 = (1.0f - fy) * fx * vy0 * vx1;
      const float w10 = fy * (1.0f - fx) * vy1 * vx0;
      const float w11 = fy * fx * vy1 * vx1;
      const int cx0 = min(max(ix0, 0), NHW - 1), cx1 = min(max(ix1, 0), NHW - 1);
      const int cy0 = min(max(iy0, 0), NHW - 1), cy1 = min(max(iy1, 0), NHW - 1);
      const float* q00 = mb + (size_t)(cy0 * NHW + cx0) * NC + gchunk * 8;
      const float* q01 = mb + (size_t)(cy0 * NHW + cx1) * NC + gchunk * 8;
      const float* q10 = mb + (size_t)(cy1 * NHW + cx0) * NC + gchunk * 8;
      const float* q11 = mb + (size_t)(cy1 * NHW + cx1) * NC + gchunk * 8;
      f32x4 v00a = *(const f32x4*)q00, v00b = *(const f32x4*)(q00 + 4);
      f32x4 v01a = *(const f32x4*)q01, v01b = *(const f32x4*)(q01 + 4);
      f32x4 v10a = *(const f32x4*)q10, v10b = *(const f32x4*)(q10 + 4);
      f32x4 v11a = *(const f32x4*)q11, v11b = *(const f32x4*)(q11 + 4);
      f32x4 ra = v00a * w00 + v01a * w01 + v10a * w10 + v11a * w11;
      f32x4 rb = v00b * w00 + v01b * w01 + v10b * w10 + v11b * w11;
      ushortx8 pk;
      pk[0] = f2bf(ra.x); pk[1] = f2bf(ra.y); pk[2] = f2bf(ra.z); pk[3] = f2bf(ra.w);
      pk[4] = f2bf(rb.x); pk[5] = f2bf(rb.y); pk[6] = f2bf(rb.z); pk[7] = f2bf(rb.w);
      const int slot = gchunk * 32 + (m ^ (gchunk & 15));
      *(ushortx8*)(Alds + slot * 8) = pk;
    }
    __syncthreads();
    const size_t rbase = (size_t)r * 32;
#pragma unroll
    for (int kstep = 0; kstep < 8; ++kstep) {
      const int chunk = kstep * 4 + ksub;
      const int sa0 = chunk * 32 + (lr ^ (chunk & 15));
      const int sa1 = chunk * 32 + ((16 + lr) ^ (chunk & 15));
      ushortx8 ua0 = *(const ushortx8*)(Alds + sa0 * 8);
      ushortx8 ua1 = *(const ushortx8*)(Alds + sa1 * 8);
      const unsigned short* bp = W2s + (rbase + chunk) * 2048 + (o0 + lr) * 8;
      ushortx8 ub0 = *(const ushortx8*)bp;
      ushortx8 ub1 = *(const ushortx8*)(bp + 128);
      bf16x8 fa0 = __builtin_bit_cast(bf16x8, ua0);
      bf16x8 fa1 = __builtin_bit_cast(bf16x8, ua1);
      bf16x8 fb0 = __builtin_bit_cast(bf16x8, ub0);
      bf16x8 fb1 = __builtin_bit_cast(bf16x8, ub1);
      acc[0][0] = __builtin_amdgcn_mfma_f32_16x16x32_bf16(fa0, fb0, acc[0][0], 0, 0, 0);
      acc[1][0] = __builtin_amdgcn_mfma_f32_16x16x32_bf16(fa1, fb0, acc[1][0], 0, 0, 0);
      acc[0][1] = __builtin_amdgcn_mfma_f32_16x16x32_bf16(fa0, fb1, acc[0][1], 0, 0, 0);
      acc[1][1] = __builtin_amdgcn_mfma_f32_16x16x32_bf16(fa1, fb1, acc[1][1], 0, 0, 0);
    }
  }
  // epilogue. C/D: col=lane&15, row=(lane>>4)*4+reg
  if (PART) {
    float* dst = PART + (size_t)kk8 * (MR * NC);
#pragma unroll
    for (int mf = 0; mf < 2; ++mf)
#pragma unroll
      for (int nf = 0; nf < 2; ++nf) {
        const int o = o0 + nf * 16 + lr;
#pragma unroll
        for (int reg = 0; reg < 4; ++reg) {
          const int mrow = mf * 16 + ksub * 4 + reg;
          dst[(size_t)(n0 + mrow) * 256 + o] = acc[mf][nf][reg];
        }
      }
  } else {
#pragma unroll
    for (int mf = 0; mf < 2; ++mf)
#pragma unroll
      for (int nf = 0; nf < 2; ++nf) {
        const int o = o0 + nf * 16 + lr;
        const float bko = bk[o];
#pragma unroll
        for (int reg = 0; reg < 4; ++reg) {
          const int mrow = mf * 16 + ksub * 4 + reg;
          float v = acc[mf][nf][reg] + bko;
          v = v > 0.0f ? v : 0.0f;
          CR1[(size_t)(n0 + mrow) * 256 + o] = f2bf(v);
        }
      }
  }
}

// ---------------------------------------------------------------------------
// Kernel 3b: reduce K partials + bias + relu -> bf16 CR1
__global__ __launch_bounds__(256) void k_red(
    const float* __restrict__ PART, const float* __restrict__ bk,
    unsigned short* __restrict__ CR1, int K) {
  int gid = blockIdx.x * 256 + threadIdx.x;     // one f32x4 (4 outputs) each
  size_t idx4 = (size_t)gid * 4;
  if (idx4 >= (size_t)MR * NC) return;
  f32x4 sum = *(const f32x4*)(PART + idx4);
  for (int k = 1; k < K; ++k)
    sum += *(const f32x4*)(PART + (size_t)k * (MR * NC) + idx4);
  f32x4 bv = *(const f32x4*)(bk + (idx4 & 255));
  sum += bv;
  ushortx4 pk;
#pragma unroll
  for (int e = 0; e < 4; ++e) {
    float v = sum[e] > 0.0f ? sum[e] : 0.0f;
    pk[e] = f2bf(v);
  }
  *(ushortx4*)(CR1 + idx4) = pk;
}

// ---------------------------------------------------------------------------
// Kernel 4: GEMM2  out[n,o] = sum_j CR1[n,j]*Wp[o,j] + bp[o]  (16-row tiles)
__global__ __launch_bounds__(256) void k_gemm2(
    const unsigned short* __restrict__ CR1, const unsigned short* __restrict__ WPs,
    const float* __restrict__ bp, float* __restrict__ outc) {
  const int tid = threadIdx.x;
  const int n0 = blockIdx.x * 16;
  const int lane = tid & 63;
  const int wave = tid >> 6;  // 0..3
  const int lr = lane & 15;
  const int ksub = lane >> 4;
  const int o0 = wave * 64;
  f32x4 acc[4] = {};
#pragma unroll
  for (int kstep = 0; kstep < 8; ++kstep) {
    const int t0 = kstep * 32 + ksub * 8;
    ushortx8 ua0 = *(const ushortx8*)(CR1 + (size_t)(n0 + lr) * 256 + t0);
    bf16x8 fa0 = __builtin_bit_cast(bf16x8, ua0);
    const int chunk = kstep * 4 + ksub;
#pragma unroll
    for (int nf = 0; nf < 4; ++nf) {
      ushortx8 ub = *(const ushortx8*)(WPs + (size_t)chunk * 2048 + (o0 + nf * 16 + lr) * 8);
      bf16x8 fb = __builtin_bit_cast(bf16x8, ub);
      acc[nf] = __builtin_amdgcn_mfma_f32_16x16x32_bf16(fa0, fb, acc[nf], 0, 0, 0);
    }
  }
#pragma unroll
  for (int nf = 0; nf < 4; ++nf) {
    const int o = o0 + nf * 16 + lr;
    const float bpo = bp[o];
#pragma unroll
    for (int reg = 0; reg < 4; ++reg) {
      const int mrow = ksub * 4 + reg;
      outc[(size_t)(n0 + mrow) * 256 + o] = acc[nf][reg] + bpo;
    }
  }
}

// ---------------------------------------------------------------------------
extern "C" void kernel_launch(void* const* d_in, const int* in_sizes, int n_in,
                              void* d_out, int out_size, void* d_ws, size_t ws_size,
                              hipStream_t stream) {
  (void)in_sizes; (void)n_in; (void)out_size;
  const float* polys = (const float*)d_in[1];
  const float* mem   = (const float*)d_in[2];
  const float* Wk    = (const float*)d_in[4];
  const float* bk    = (const float*)d_in[5];
  const float* Wp    = (const float*)d_in[6];
  const float* bp    = (const float*)d_in[7];
  float* out = (float*)d_out;
  float* out_pts = out + (size_t)MR * NC;   // second output: points

  // ws layout
  unsigned short* W2s = (unsigned short*)d_ws;                       // 4,718,592 B
  unsigned short* WPs = (unsigned short*)((char*)d_ws + 4718592);    //   131,072 B
  float*          PTS = (float*)((char*)d_ws + 4849664);             //   256,000 B
  unsigned short* CR1 = (unsigned short*)((char*)d_ws + 5105664);    // 4,096,000 B
  const size_t PART_OFF = 9201664;
  float*          PARTp = (float*)((char*)d_ws + PART_OFF);          // K*8,192,000 B

  int K = 1;
  if (ws_size >= PART_OFF + 4ull * 8192000ull) K = 4;
  else if (ws_size >= PART_OFF + 2ull * 8192000ull) K = 2;
  float* PART = (K > 1) ? PARTp : nullptr;

  hipLaunchKernelGGL(k_points, dim3(32), dim3(256), 0, stream, polys, out_pts, PTS);
  hipLaunchKernelGGL(k_permwk, dim3(1152), dim3(256), 0, stream, Wk, W2s);
  hipLaunchKernelGGL(k_permwp, dim3(32), dim3(256), 0, stream, Wp, WPs);
  hipLaunchKernelGGL(k_gemm1, dim3(256 * K), dim3(512), 0, stream,
                     mem, PTS, W2s, bk, PART, CR1, K);
  if (PART)
    hipLaunchKernelGGL(k_red, dim3(2000), dim3(256), 0, stream, PART, bk, CR1, K);
  hipLaunchKernelGGL(k_gemm2, dim3(500), dim3(256), 0, stream, CR1, WPs, bp, out);
}

// Round 6
// 121.376 us; speedup vs baseline: 1.8937x; 1.1102x over previous
//
#include <hip/hip_runtime.h>

// Problem constants (fixed by setup_inputs)
#define NB 16
#define NQ 500
#define NC 256
#define NHW 64
#define MR 8000            // B*Q rows
#define KD 9216            // GEMM1 K = 36*256

typedef float f32x4 __attribute__((ext_vector_type(4)));
typedef __bf16 bf16x8 __attribute__((ext_vector_type(8)));
typedef unsigned short ushortx8 __attribute__((ext_vector_type(8)));
typedef unsigned short ushortx4 __attribute__((ext_vector_type(4)));

__device__ __forceinline__ unsigned short f2bf(float f) {
  unsigned int u = __builtin_bit_cast(unsigned int, f);
  u += 0x7fffu + ((u >> 16) & 1u);   // round-to-nearest-even
  return (unsigned short)(u >> 16);
}

// ---------------------------------------------------------------------------
// Kernel 1: points [B,Q,4,2]  (output 2, also kept in ws for the gather)
__global__ void k_points(const float* __restrict__ polys,
                         float* __restrict__ outp, float* __restrict__ wsp) {
  int n = blockIdx.x * 256 + threadIdx.x;
  if (n >= MR) return;
  f32x4 ca = *(const f32x4*)(polys + (size_t)n * 8);
  f32x4 cb = *(const f32x4*)(polys + (size_t)n * 8 + 4);
  const float av[4] = {0.0f, 0.33333334f, 0.66666669f, 1.0f};
#pragma unroll
  for (int s = 0; s < 4; ++s) {
    float a1 = av[s], a2 = a1 * a1, a3 = a2 * a1;
    float v0 = ca.x * a3 + ca.y * a2 + ca.z * a1 + ca.w;
    float v1 = cb.x * a3 + cb.y * a2 + cb.z * a1 + cb.w;
    float pt0 = 2.0f * v1 - 1.0f;
    float pt1 = 2.0f * v0 - 1.0f;
    outp[(size_t)n * 8 + s * 2 + 0] = pt0;
    outp[(size_t)n * 8 + s * 2 + 1] = pt1;
    wsp[(size_t)n * 8 + s * 2 + 0] = pt0;
    wsp[(size_t)n * 8 + s * 2 + 1] = pt1;
  }
}

// ---------------------------------------------------------------------------
// Kernel 2: permute Wk -> fragment-linear bf16 W2s[t>>3][o][t&7]
__global__ void k_permwk(const float* __restrict__ Wk,
                         unsigned short* __restrict__ W2s) {
  int tid = blockIdx.x * 256 + threadIdx.x;
  if (tid >= (KD / 8) * NC) return;      // 294912
  int o = tid & 255;
  int th = tid >> 8;                     // 0..1151  (= t>>3)
  int r = th >> 5;                       // sample slot 0..35
  int cbase = (th & 31) * 8;
  int np = r / 9;
  int kl = r - np * 9;
  int kk = kl / 3;
  int ll = kl - kk * 3;
  const float* src = Wk + (size_t)o * KD + (size_t)(np * 256 + cbase) * 9 + kk * 3 + ll;
  ushortx8 v;
#pragma unroll
  for (int j = 0; j < 8; ++j) v[j] = f2bf(src[(size_t)j * 9]);
  *(ushortx8*)(W2s + (size_t)th * 2048 + o * 8) = v;
}

// Kernel 2b: permute Wp -> fragment-linear bf16 WPs[j>>3][o][j&7]
__global__ void k_permwp(const float* __restrict__ Wp,
                         unsigned short* __restrict__ WPs) {
  int tid = blockIdx.x * 256 + threadIdx.x;
  if (tid >= 32 * 256) return;
  int o = tid & 255;
  int th = tid >> 8;
  const float* src = Wp + (size_t)o * 256 + th * 8;
  ushortx8 v;
#pragma unroll
  for (int j = 0; j < 8; ++j) v[j] = f2bf(src[j]);
  *(ushortx8*)(WPs + (size_t)th * 2048 + o * 8) = v;
}

// ---------------------------------------------------------------------------
// Kernel 3: fused gather + GEMM1, M-tile = 64 rows, split-K over sample slots.
// Decomposition: x=bid&7, kk8=(bid>>3)%K, j=bid/(8K), t=x+8j, guard t>=125;
// contiguous reindex tt = 16x - max(x-5,0) + j  (tiles_x = 16,16,16,16,16,15,15,15).
// Double-buffered A-LDS, ONE barrier per slot:
//   per slot r: gather->write buf[r&1]; barrier; mfma reads buf[r&1].
//   write(r+2) to buf[r&1] happens after barrier(r+1), which each wave only
//   reaches after finishing its mfma(r) reads -> distance-2 reuse is safe.
__global__ __launch_bounds__(512, 4) void k_gemm1(
    const float* __restrict__ mem, const float* __restrict__ pts,
    const unsigned short* __restrict__ W2s, const float* __restrict__ bk,
    float* __restrict__ PART, unsigned short* __restrict__ CR1, int K) {
  __shared__ __align__(16) unsigned short Alds[2 * 2048 * 8];  // 64 KB

  const int bid = blockIdx.x;
  const int x = bid & 7;
  const int kk8 = (bid >> 3) % K;
  const int j = bid / (8 * K);
  const int t = x + 8 * j;
  if (t >= 125) return;
  const int tt = 16 * x - ((x > 5) ? (x - 5) : 0) + j;   // contiguous tile id
  const int nsl = 36 / K;
  const int r0 = kk8 * nsl;

  const int tid = threadIdx.x;
  const int n0 = tt * 64;
  const int lane = tid & 63;
  const int wave = tid >> 6;   // 0..7
  const int lr = lane & 15;
  const int ksub = lane >> 4;
  const int o0 = wave * 32;

  const int gchunk = tid & 31;
  const int gm0 = tid >> 5;    // 0..15 ; tasks handle rows gm0+16*task, task 0..3

  // per-task row/batch bases
  size_t boff[4];
  int nrow[4];
#pragma unroll
  for (int task = 0; task < 4; ++task) {
    nrow[task] = n0 + gm0 + 16 * task;
    boff[task] = (size_t)(nrow[task] / NQ) * (NHW * NHW * NC);
  }

  f32x4 acc[4][2] = {};

  for (int r = r0; r < r0 + nsl; ++r) {
    const int s = r & 3;
    const int mm = r >> 2;
    // delta(a) = (1.5a-2)/32, exact in fp32; DHX = delta(mm/3), DWY = delta(mm%3)
    const int mdiv = (mm * 11) >> 5;          // mm/3 for mm in [0,9)
    const int mmod = mm - 3 * mdiv;
    const float dhx = (1.5f * (float)mdiv - 2.0f) * 0.03125f;
    const float dwy = (1.5f * (float)mmod - 2.0f) * 0.03125f;
    const int lbase = ((r - r0) & 1) * 2048;   // LDS buffer select
#pragma unroll 2
    for (int task = 0; task < 4; ++task) {
      const int m = gm0 + task * 16;
      const int n = nrow[task];
      const float* mb = mem + boff[task];
      const float p0 = pts[(size_t)n * 8 + s * 2 + 0];
      const float p1 = pts[(size_t)n * 8 + s * 2 + 1];
      // grid[...,0] (points[...,0]+delta_h) drives COLUMN; [...,1] drives ROW.
      const float gx = (p0 + dhx + 1.0f) * 0.5f * 63.0f;  // column
      const float gy = (p1 + dwy + 1.0f) * 0.5f * 63.0f;  // row
      const float x0f = floorf(gx), y0f = floorf(gy);
      const float fx = gx - x0f, fy = gy - y0f;
      const int ix0 = (int)x0f, iy0 = (int)y0f;
      const int ix1 = ix0 + 1, iy1 = iy0 + 1;
      const float vx0 = (ix0 >= 0 && ix0 < NHW) ? 1.0f : 0.0f;
      const float vx1 = (ix1 >= 0 && ix1 < NHW) ? 1.0f : 0.0f;
      const float vy0 = (iy0 >= 0 && iy0 < NHW) ? 1.0f : 0.0f;
      const float vy1 = (iy1 >= 0 && iy1 < NHW) ? 1.0f : 0.0f;
      const float w00 = (1.0f - fy) * (1.0f - fx) * vy0 * vx0;
      const float w01 = (1.0f - fy) * fx * vy0 * vx1;
      const float w10 = fy * (1.0f - fx) * vy1 * vx0;
      const float w11 = fy * fx * vy1 * vx1;
      const int cx0 = min(max(ix0, 0), NHW - 1), cx1 = min(max(ix1, 0), NHW - 1);
      const int cy0 = min(max(iy0, 0), NHW - 1), cy1 = min(max(iy1, 0), NHW - 1);
      const float* q00 = mb + (size_t)(cy0 * NHW + cx0) * NC + gchunk * 8;
      const float* q01 = mb + (size_t)(cy0 * NHW + cx1) * NC + gchunk * 8;
      const float* q10 = mb + (size_t)(cy1 * NHW + cx0) * NC + gchunk * 8;
      const float* q11 = mb + (size_t)(cy1 * NHW + cx1) * NC + gchunk * 8;
      f32x4 v00a = *(const f32x4*)q00, v00b = *(const f32x4*)(q00 + 4);
      f32x4 v01a = *(const f32x4*)q01, v01b = *(const f32x4*)(q01 + 4);
      f32x4 v10a = *(const f32x4*)q10, v10b = *(const f32x4*)(q10 + 4);
      f32x4 v11a = *(const f32x4*)q11, v11b = *(const f32x4*)(q11 + 4);
      f32x4 ra = v00a * w00 + v01a * w01 + v10a * w10 + v11a * w11;
      f32x4 rb = v00b * w00 + v01b * w01 + v10b * w10 + v11b * w11;
      ushortx8 pk;
      pk[0] = f2bf(ra.x); pk[1] = f2bf(ra.y); pk[2] = f2bf(ra.z); pk[3] = f2bf(ra.w);
      pk[4] = f2bf(rb.x); pk[5] = f2bf(rb.y); pk[6] = f2bf(rb.z); pk[7] = f2bf(rb.w);
      const int slot = lbase + gchunk * 64 + (m ^ (gchunk & 15));
      *(ushortx8*)(Alds + slot * 8) = pk;
    }
    __syncthreads();
    const size_t rbase = (size_t)r * 32;
#pragma unroll
    for (int kstep = 0; kstep < 8; ++kstep) {
      const int chunk = kstep * 4 + ksub;
      const unsigned short* bp = W2s + (rbase + chunk) * 2048 + (o0 + lr) * 8;
      ushortx8 ub0 = *(const ushortx8*)bp;
      ushortx8 ub1 = *(const ushortx8*)(bp + 128);
      bf16x8 fb0 = __builtin_bit_cast(bf16x8, ub0);
      bf16x8 fb1 = __builtin_bit_cast(bf16x8, ub1);
#pragma unroll
      for (int mf = 0; mf < 4; ++mf) {
        const int sa = lbase + chunk * 64 + ((mf * 16 + lr) ^ (chunk & 15));
        ushortx8 ua = *(const ushortx8*)(Alds + sa * 8);
        bf16x8 fa = __builtin_bit_cast(bf16x8, ua);
        acc[mf][0] = __builtin_amdgcn_mfma_f32_16x16x32_bf16(fa, fb0, acc[mf][0], 0, 0, 0);
        acc[mf][1] = __builtin_amdgcn_mfma_f32_16x16x32_bf16(fa, fb1, acc[mf][1], 0, 0, 0);
      }
    }
  }
  // epilogue. C/D: col=lane&15, row=(lane>>4)*4+reg
  if (PART) {
    float* dst = PART + (size_t)kk8 * (MR * NC);
#pragma unroll
    for (int mf = 0; mf < 4; ++mf)
#pragma unroll
      for (int nf = 0; nf < 2; ++nf) {
        const int o = o0 + nf * 16 + lr;
#pragma unroll
        for (int reg = 0; reg < 4; ++reg) {
          const int mrow = mf * 16 + ksub * 4 + reg;
          dst[(size_t)(n0 + mrow) * 256 + o] = acc[mf][nf][reg];
        }
      }
  } else {
#pragma unroll
    for (int mf = 0; mf < 4; ++mf)
#pragma unroll
      for (int nf = 0; nf < 2; ++nf) {
        const int o = o0 + nf * 16 + lr;
        const float bko = bk[o];
#pragma unroll
        for (int reg = 0; reg < 4; ++reg) {
          const int mrow = mf * 16 + ksub * 4 + reg;
          float v = acc[mf][nf][reg] + bko;
          v = v > 0.0f ? v : 0.0f;
          CR1[(size_t)(n0 + mrow) * 256 + o] = f2bf(v);
        }
      }
  }
}

// ---------------------------------------------------------------------------
// Kernel 3b: reduce K partials + bias + relu -> bf16 CR1
__global__ __launch_bounds__(256) void k_red(
    const float* __restrict__ PART, const float* __restrict__ bk,
    unsigned short* __restrict__ CR1, int K) {
  int gid = blockIdx.x * 256 + threadIdx.x;     // one f32x4 (4 outputs) each
  size_t idx4 = (size_t)gid * 4;
  if (idx4 >= (size_t)MR * NC) return;
  f32x4 sum = *(const f32x4*)(PART + idx4);
  for (int k = 1; k < K; ++k)
    sum += *(const f32x4*)(PART + (size_t)k * (MR * NC) + idx4);
  f32x4 bv = *(const f32x4*)(bk + (idx4 & 255));
  sum += bv;
  ushortx4 pk;
#pragma unroll
  for (int e = 0; e < 4; ++e) {
    float v = sum[e] > 0.0f ? sum[e] : 0.0f;
    pk[e] = f2bf(v);
  }
  *(ushortx4*)(CR1 + idx4) = pk;
}

// ---------------------------------------------------------------------------
// Kernel 4: GEMM2  out[n,o] = sum_j CR1[n,j]*Wp[o,j] + bp[o]  (16-row tiles)
__global__ __launch_bounds__(256) void k_gemm2(
    const unsigned short* __restrict__ CR1, const unsigned short* __restrict__ WPs,
    const float* __restrict__ bp, float* __restrict__ outc) {
  const int tid = threadIdx.x;
  const int n0 = blockIdx.x * 16;
  const int lane = tid & 63;
  const int wave = tid >> 6;  // 0..3
  const int lr = lane & 15;
  const int ksub = lane >> 4;
  const int o0 = wave * 64;
  f32x4 acc[4] = {};
#pragma unroll
  for (int kstep = 0; kstep < 8; ++kstep) {
    const int t0 = kstep * 32 + ksub * 8;
    ushortx8 ua0 = *(const ushortx8*)(CR1 + (size_t)(n0 + lr) * 256 + t0);
    bf16x8 fa0 = __builtin_bit_cast(bf16x8, ua0);
    const int chunk = kstep * 4 + ksub;
#pragma unroll
    for (int nf = 0; nf < 4; ++nf) {
      ushortx8 ub = *(const ushortx8*)(WPs + (size_t)chunk * 2048 + (o0 + nf * 16 + lr) * 8);
      bf16x8 fb = __builtin_bit_cast(bf16x8, ub);
      acc[nf] = __builtin_amdgcn_mfma_f32_16x16x32_bf16(fa0, fb, acc[nf], 0, 0, 0);
    }
  }
#pragma unroll
  for (int nf = 0; nf < 4; ++nf) {
    const int o = o0 + nf * 16 + lr;
    const float bpo = bp[o];
#pragma unroll
    for (int reg = 0; reg < 4; ++reg) {
      const int mrow = ksub * 4 + reg;
      outc[(size_t)(n0 + mrow) * 256 + o] = acc[nf][reg] + bpo;
    }
  }
}

// ---------------------------------------------------------------------------
extern "C" void kernel_launch(void* const* d_in, const int* in_sizes, int n_in,
                              void* d_out, int out_size, void* d_ws, size_t ws_size,
                              hipStream_t stream) {
  (void)in_sizes; (void)n_in; (void)out_size;
  const float* polys = (const float*)d_in[1];
  const float* mem   = (const float*)d_in[2];
  const float* Wk    = (const float*)d_in[4];
  const float* bk    = (const float*)d_in[5];
  const float* Wp    = (const float*)d_in[6];
  const float* bp    = (const float*)d_in[7];
  float* out = (float*)d_out;
  float* out_pts = out + (size_t)MR * NC;   // second output: points

  // ws layout
  unsigned short* W2s = (unsigned short*)d_ws;                       // 4,718,592 B
  unsigned short* WPs = (unsigned short*)((char*)d_ws + 4718592);    //   131,072 B
  float*          PTS = (float*)((char*)d_ws + 4849664);             //   256,000 B
  unsigned short* CR1 = (unsigned short*)((char*)d_ws + 5105664);    // 4,096,000 B
  const size_t PART_OFF = 9201664;
  float*          PARTp = (float*)((char*)d_ws + PART_OFF);          // K*8,192,000 B

  int K = 1;
  if (ws_size >= PART_OFF + 4ull * 8192000ull) K = 4;
  else if (ws_size >= PART_OFF + 2ull * 8192000ull) K = 2;
  float* PART = (K > 1) ? PARTp : nullptr;

  hipLaunchKernelGGL(k_points, dim3(32), dim3(256), 0, stream, polys, out_pts, PTS);
  hipLaunchKernelGGL(k_permwk, dim3(1152), dim3(256), 0, stream, Wk, W2s);
  hipLaunchKernelGGL(k_permwp, dim3(32), dim3(256), 0, stream, Wp, WPs);
  hipLaunchKernelGGL(k_gemm1, dim3(128 * K), dim3(512), 0, stream,
                     mem, PTS, W2s, bk, PART, CR1, K);
  if (PART)
    hipLaunchKernelGGL(k_red, dim3(2000), dim3(256), 0, stream, PART, bk, CR1, K);
  hipLaunchKernelGGL(k_gemm2, dim3(500), dim3(256), 0, stream, CR1, WPs, bp, out);
}